// Round 1
// baseline (1127.881 us; speedup 1.0000x reference)
//
#include <hip/hip_runtime.h>
#include <math.h>

#define D_MODEL 2048
#define NH 16
#define DH 128
#define SEQ 2048
#define NBH 32  // batch * heads

typedef unsigned short u16;
typedef unsigned int u32;
typedef __attribute__((ext_vector_type(8))) short short8;
typedef __attribute__((ext_vector_type(4))) float floatx4;
typedef __attribute__((ext_vector_type(4))) unsigned short ushort4v;

__device__ __forceinline__ u16 f2bf(float f) {
  u32 u = __builtin_bit_cast(u32, f);
  return (u16)((u + 0x8000u) >> 16);  // round-to-nearest (ties up) — cheap, 2 VALU
}
__device__ __forceinline__ float bf2f(u16 h) {
  return __builtin_bit_cast(float, (u32)h << 16);
}

// ---------------------------------------------------------------------------
// C = A(MxK) * W(NxK)^T + bias.  A row-major (f32 or bf16), W f32 row-major.
// mode 0/1: write bf16 (b,h,s,d)   [Q,K]
// mode 2:   write bf16 (b,h,d,s)   [V transposed for PV B-operand]
// mode 3:   write f32  (M x N)     [output projection]
// 128x128 tile, BK=64, 256 threads (4 waves), 4x4 16x16 MFMA tiles per wave.
// LDS padded stride 72 elems (144 B) -> 2-way bank aliasing (free).
// ---------------------------------------------------------------------------
template <int ABF16>
__global__ __launch_bounds__(256, 2) void gemm_kernel(
    const void* __restrict__ Aptr, const float* __restrict__ W,
    const float* __restrict__ bias, void* __restrict__ Cptr, const int mode) {
  __shared__ u16 As[128 * 72];
  __shared__ u16 Bs[128 * 72];
  const int tid = threadIdx.x;
  const int wave = tid >> 6, lane = tid & 63;
  const int lr = lane & 15, lg = lane >> 4;
  const int m0 = blockIdx.y * 128, n0 = blockIdx.x * 128;
  const int wm = (wave & 1) * 64, wn = (wave >> 1) * 64;

  floatx4 acc[4][4];
#pragma unroll
  for (int i = 0; i < 4; ++i)
#pragma unroll
    for (int j = 0; j < 4; ++j) {
      floatx4 z = {0.f, 0.f, 0.f, 0.f};
      acc[i][j] = z;
    }

  for (int kt = 0; kt < D_MODEL; kt += 64) {
    if (ABF16) {
      const u16* A = (const u16*)Aptr;
      const int row0 = tid >> 3, c8 = (tid & 7) * 8;
#pragma unroll
      for (int p = 0; p < 4; ++p) {
        const int row = row0 + p * 32;
        *(short8*)&As[row * 72 + c8] =
            *(const short8*)(A + (size_t)(m0 + row) * D_MODEL + kt + c8);
      }
    } else {
      const float* A = (const float*)Aptr;
      const int row0 = tid >> 4, c4 = (tid & 15) * 4;
#pragma unroll
      for (int p = 0; p < 8; ++p) {
        const int row = row0 + p * 16;
        const floatx4 v =
            *(const floatx4*)(A + (size_t)(m0 + row) * D_MODEL + kt + c4);
        ushort4v h;
        h[0] = f2bf(v[0]); h[1] = f2bf(v[1]); h[2] = f2bf(v[2]); h[3] = f2bf(v[3]);
        *(ushort4v*)&As[row * 72 + c4] = h;
      }
    }
    {
      const int row0 = tid >> 4, c4 = (tid & 15) * 4;
#pragma unroll
      for (int p = 0; p < 8; ++p) {
        const int row = row0 + p * 16;
        const floatx4 v =
            *(const floatx4*)(W + (size_t)(n0 + row) * D_MODEL + kt + c4);
        ushort4v h;
        h[0] = f2bf(v[0]); h[1] = f2bf(v[1]); h[2] = f2bf(v[2]); h[3] = f2bf(v[3]);
        *(ushort4v*)&Bs[row * 72 + c4] = h;
      }
    }
    __syncthreads();
#pragma unroll
    for (int ks = 0; ks < 2; ++ks) {
      short8 af[4], bfr[4];
#pragma unroll
      for (int i = 0; i < 4; ++i)
        af[i] = *(const short8*)&As[(wm + 16 * i + lr) * 72 + ks * 32 + lg * 8];
#pragma unroll
      for (int j = 0; j < 4; ++j)
        bfr[j] = *(const short8*)&Bs[(wn + 16 * j + lr) * 72 + ks * 32 + lg * 8];
#pragma unroll
      for (int i = 0; i < 4; ++i)
#pragma unroll
        for (int j = 0; j < 4; ++j)
          acc[i][j] = __builtin_amdgcn_mfma_f32_16x16x32_bf16(af[i], bfr[j],
                                                              acc[i][j], 0, 0, 0);
    }
    __syncthreads();
  }

  // epilogue
  float bj[4];
  int ncol[4];
#pragma unroll
  for (int j = 0; j < 4; ++j) {
    ncol[j] = n0 + wn + 16 * j + lr;
    bj[j] = bias[ncol[j]];
  }

  if (mode == 3) {
    float* C = (float*)Cptr;
#pragma unroll
    for (int i = 0; i < 4; ++i)
#pragma unroll
      for (int r = 0; r < 4; ++r) {
        const int m = m0 + wm + 16 * i + lg * 4 + r;
#pragma unroll
        for (int j = 0; j < 4; ++j)
          C[(size_t)m * D_MODEL + ncol[j]] = acc[i][j][r] + bj[j];
      }
  } else if (mode == 2) {
    u16* C = (u16*)Cptr;
#pragma unroll
    for (int i = 0; i < 4; ++i)
#pragma unroll
      for (int r = 0; r < 4; ++r) {
        const int m = m0 + wm + 16 * i + lg * 4 + r;
        const int b = m >> 11, s = m & (SEQ - 1);
#pragma unroll
        for (int j = 0; j < 4; ++j) {
          const int h = ncol[j] >> 7, d = ncol[j] & (DH - 1);
          C[((size_t)((b * NH + h) * DH + d)) * SEQ + s] = f2bf(acc[i][j][r] + bj[j]);
        }
      }
  } else {
    u16* C = (u16*)Cptr;
#pragma unroll
    for (int i = 0; i < 4; ++i)
#pragma unroll
      for (int r = 0; r < 4; ++r) {
        const int m = m0 + wm + 16 * i + lg * 4 + r;
        const int b = m >> 11, s = m & (SEQ - 1);
#pragma unroll
        for (int j = 0; j < 4; ++j) {
          const int h = ncol[j] >> 7, d = ncol[j] & (DH - 1);
          C[((size_t)((b * NH + h) * SEQ + s)) * DH + d] = f2bf(acc[i][j][r] + bj[j]);
        }
      }
  }
}

// ---------------------------------------------------------------------------
// RoPE in-place on bf16 Q and K, layout (b,h,s,d). One thread per (bh,s,pair).
// ref: i = 2p, freq = theta^(-2p/128) = 2^(-p/64 * log2(1e4)), angle = s*freq.
// ---------------------------------------------------------------------------
__global__ void rope_kernel(u16* __restrict__ Q, u16* __restrict__ K) {
  const int idx = blockIdx.x * blockDim.x + threadIdx.x;
  const int p = idx & 63;
  const int s = (idx >> 6) & (SEQ - 1);
  const int bh = idx >> 17;
  if (bh >= NBH) return;
  const float freq = exp2f(-(float)p * (13.287712379549449f / 64.0f));
  const float ang = (float)s * freq;
  float sn, cs;
  sincosf(ang, &sn, &cs);
  const size_t base = ((size_t)bh * SEQ + s) * DH + 2 * p;
  {
    const u32 qq = *(const u32*)(Q + base);
    const float x1 = bf2f((u16)(qq & 0xffffu)), x2 = bf2f((u16)(qq >> 16));
    *(u32*)(Q + base) =
        (u32)f2bf(x1 * cs - x2 * sn) | ((u32)f2bf(x1 * sn + x2 * cs) << 16);
  }
  {
    const u32 kk = *(const u32*)(K + base);
    const float x1 = bf2f((u16)(kk & 0xffffu)), x2 = bf2f((u16)(kk >> 16));
    *(u32*)(K + base) =
        (u32)f2bf(x1 * cs - x2 * sn) | ((u32)f2bf(x1 * sn + x2 * cs) << 16);
  }
}

// ---------------------------------------------------------------------------
// Flash attention, causal. Block = (qt, bh): 128 q-rows, k-tiles of 64.
// 4 waves; wave owns 32 q-rows (2 m-tiles). Q fragments in registers.
// K staged (64 x 128, stride 136), Vt staged (128 x 64, stride 72),
// P round-trips through per-wave LDS (32 x 64, stride 72) C-layout->A-layout.
// Output written bf16 to (b, s, h*128+d) for the O-projection GEMM.
// ---------------------------------------------------------------------------
__global__ __launch_bounds__(256, 2) void attn_kernel(
    const u16* __restrict__ Q, const u16* __restrict__ K,
    const u16* __restrict__ Vt, u16* __restrict__ Oflat) {
  __shared__ u16 Ks[64 * 136];
  __shared__ u16 Vts[128 * 72];
  __shared__ u16 Ps[4 * 32 * 72];
  const int tid = threadIdx.x;
  const int wave = tid >> 6, lane = tid & 63;
  const int lr = lane & 15, lg = lane >> 4;
  const int qt = blockIdx.x, bh = blockIdx.y;
  const size_t qk0 = (size_t)bh * SEQ * DH;
  const int q0 = qt * 128 + wave * 32;
  const float scale = 0.08838834764831845f;  // 1/sqrt(128)
  const float L2E = 1.4426950408889634f;

  short8 qf[2][4];
#pragma unroll
  for (int i = 0; i < 2; ++i)
#pragma unroll
    for (int kb = 0; kb < 4; ++kb)
      qf[i][kb] = *(const short8*)(Q + qk0 + (size_t)(q0 + 16 * i + lr) * DH +
                                   kb * 32 + lg * 8);

  floatx4 o[2][8];
#pragma unroll
  for (int i = 0; i < 2; ++i)
#pragma unroll
    for (int jd = 0; jd < 8; ++jd) {
      floatx4 z = {0.f, 0.f, 0.f, 0.f};
      o[i][jd] = z;
    }
  float mrun[2][4], lrun[2][4];
#pragma unroll
  for (int i = 0; i < 2; ++i)
#pragma unroll
    for (int r = 0; r < 4; ++r) {
      mrun[i][r] = -1e38f;
      lrun[i][r] = 0.f;
    }

  u16* myP = &Ps[wave * 32 * 72];
  const int nkt = 2 * qt + 2;
  for (int kt = 0; kt < nkt; ++kt) {
    {
      const int row0 = tid >> 4, c8 = (tid & 15) * 8;
#pragma unroll
      for (int p = 0; p < 4; ++p) {
        const int r_ = row0 + p * 16;
        *(short8*)&Ks[r_ * 136 + c8] =
            *(const short8*)(K + qk0 + (size_t)(kt * 64 + r_) * DH + c8);
      }
    }
    {
      const int row0 = tid >> 3, c8 = (tid & 7) * 8;
#pragma unroll
      for (int p = 0; p < 4; ++p) {
        const int r_ = row0 + p * 32;
        *(short8*)&Vts[r_ * 72 + c8] = *(const short8*)(
            Vt + (size_t)bh * DH * SEQ + (size_t)r_ * SEQ + kt * 64 + c8);
      }
    }
    __syncthreads();

    // S = (Q K^T) strip: 32 rows x 64 cols per wave
    floatx4 sacc[2][4];
#pragma unroll
    for (int i = 0; i < 2; ++i)
#pragma unroll
      for (int j = 0; j < 4; ++j) {
        floatx4 z = {0.f, 0.f, 0.f, 0.f};
        sacc[i][j] = z;
      }
#pragma unroll
    for (int kb = 0; kb < 4; ++kb) {
      short8 kf[4];
#pragma unroll
      for (int j = 0; j < 4; ++j)
        kf[j] = *(const short8*)&Ks[(16 * j + lr) * 136 + kb * 32 + lg * 8];
#pragma unroll
      for (int i = 0; i < 2; ++i)
#pragma unroll
        for (int j = 0; j < 4; ++j)
          sacc[i][j] = __builtin_amdgcn_mfma_f32_16x16x32_bf16(qf[i][kb], kf[j],
                                                               sacc[i][j], 0, 0, 0);
    }

    // scale + causal mask (only last two k-tiles can clip)
    const bool mask_tile = (kt >= 2 * qt);
#pragma unroll
    for (int i = 0; i < 2; ++i)
#pragma unroll
      for (int j = 0; j < 4; ++j)
#pragma unroll
        for (int r = 0; r < 4; ++r) {
          float v = sacc[i][j][r] * scale;
          if (mask_tile) {
            const int kpos = kt * 64 + 16 * j + lr;
            const int qpos = q0 + 16 * i + lg * 4 + r;
            if (kpos > qpos) v = -1e30f;
          }
          sacc[i][j][r] = v;
        }

    // online softmax: row stats live in lanes sharing lg; reduce over lr (16)
    float mnew[2][4], alpha[2][4], rs[2][4];
#pragma unroll
    for (int i = 0; i < 2; ++i)
#pragma unroll
      for (int r = 0; r < 4; ++r) {
        float mx = fmaxf(fmaxf(sacc[i][0][r], sacc[i][1][r]),
                         fmaxf(sacc[i][2][r], sacc[i][3][r]));
#pragma unroll
        for (int d = 1; d < 16; d <<= 1) mx = fmaxf(mx, __shfl_xor(mx, d, 64));
        const float mn = fmaxf(mrun[i][r], mx);
        mnew[i][r] = mn;
        alpha[i][r] = exp2f((mrun[i][r] - mn) * L2E);
        mrun[i][r] = mn;
        rs[i][r] = 0.f;
      }

#pragma unroll
    for (int i = 0; i < 2; ++i)
#pragma unroll
      for (int j = 0; j < 4; ++j)
#pragma unroll
        for (int r = 0; r < 4; ++r) {
          const float pv = exp2f((sacc[i][j][r] - mnew[i][r]) * L2E);
          rs[i][r] += pv;
          myP[(16 * i + lg * 4 + r) * 72 + 16 * j + lr] = f2bf(pv);
        }

#pragma unroll
    for (int i = 0; i < 2; ++i)
#pragma unroll
      for (int r = 0; r < 4; ++r) {
        float s_ = rs[i][r];
#pragma unroll
        for (int d = 1; d < 16; d <<= 1) s_ += __shfl_xor(s_, d, 64);
        lrun[i][r] = lrun[i][r] * alpha[i][r] + s_;
      }

#pragma unroll
    for (int i = 0; i < 2; ++i)
#pragma unroll
      for (int jd = 0; jd < 8; ++jd)
#pragma unroll
        for (int r = 0; r < 4; ++r) o[i][jd][r] *= alpha[i][r];

    // drain our ds_writes of P before reading them back as A-fragments
    asm volatile("s_waitcnt lgkmcnt(0)" ::: "memory");

#pragma unroll
    for (int kb = 0; kb < 2; ++kb) {
      short8 pf[2];
#pragma unroll
      for (int i = 0; i < 2; ++i)
        pf[i] = *(const short8*)&myP[(16 * i + lr) * 72 + kb * 32 + lg * 8];
#pragma unroll
      for (int jd = 0; jd < 8; ++jd) {
        const short8 vf =
            *(const short8*)&Vts[(16 * jd + lr) * 72 + kb * 32 + lg * 8];
#pragma unroll
        for (int i = 0; i < 2; ++i)
          o[i][jd] = __builtin_amdgcn_mfma_f32_16x16x32_bf16(pf[i], vf, o[i][jd],
                                                             0, 0, 0);
      }
    }
    __syncthreads();
  }

  const int b = bh >> 4, h = bh & (NH - 1);
#pragma unroll
  for (int i = 0; i < 2; ++i)
#pragma unroll
    for (int r = 0; r < 4; ++r) {
      const int qpos = q0 + 16 * i + lg * 4 + r;
      const float inv = 1.0f / lrun[i][r];
      u16* dst = Oflat + ((size_t)(b * SEQ + qpos)) * D_MODEL + h * DH;
#pragma unroll
      for (int jd = 0; jd < 8; ++jd) dst[16 * jd + lr] = f2bf(o[i][jd][r] * inv);
    }
}

// ---------------------------------------------------------------------------
extern "C" void kernel_launch(void* const* d_in, const int* in_sizes, int n_in,
                              void* d_out, int out_size, void* d_ws,
                              size_t ws_size, hipStream_t stream) {
  const float* x = (const float*)d_in[0];
  const float* Wq = (const float*)d_in[1];
  const float* bq = (const float*)d_in[2];
  const float* Wk = (const float*)d_in[3];
  const float* bk = (const float*)d_in[4];
  const float* Wv = (const float*)d_in[5];
  const float* bv = (const float*)d_in[6];
  const float* Wo = (const float*)d_in[7];
  const float* bo = (const float*)d_in[8];
  float* out = (float*)d_out;

  // workspace layout (bf16): q | k | vt | attn_flat  = 4 * 16 MB = 64 MB
  u16* q = (u16*)d_ws;
  u16* k = q + (size_t)NBH * SEQ * DH;
  u16* vt = k + (size_t)NBH * SEQ * DH;
  u16* aflat = vt + (size_t)NBH * SEQ * DH;

  const dim3 gg(D_MODEL / 128, (2 * SEQ) / 128);  // (16, 32)
  const dim3 gb(256);

  gemm_kernel<0><<<gg, gb, 0, stream>>>(x, Wq, bq, q, 0);
  gemm_kernel<0><<<gg, gb, 0, stream>>>(x, Wk, bk, k, 1);
  gemm_kernel<0><<<gg, gb, 0, stream>>>(x, Wv, bv, vt, 2);
  rope_kernel<<<dim3((NBH * SEQ * (DH / 2)) / 256), dim3(256), 0, stream>>>(q, k);
  attn_kernel<<<dim3(SEQ / 128, NBH), gb, 0, stream>>>(q, k, vt, aflat);
  gemm_kernel<1><<<gg, gb, 0, stream>>>(aflat, Wo, bo, out, 3);
}

// Round 2
// 519.239 us; speedup vs baseline: 2.1722x; 2.1722x over previous
//
#include <hip/hip_runtime.h>
#include <math.h>

#define D_MODEL 2048
#define NH 16
#define DH 128
#define SEQ 2048
#define NBH 32  // batch * heads

typedef unsigned short u16;
typedef unsigned int u32;
typedef __attribute__((ext_vector_type(8))) short short8;
typedef __attribute__((ext_vector_type(4))) float floatx4;
typedef __attribute__((ext_vector_type(4))) unsigned short ushort4v;

__device__ __forceinline__ u16 f2bf(float f) {
  u32 u = __builtin_bit_cast(u32, f);
  return (u16)((u + 0x8000u) >> 16);
}
__device__ __forceinline__ float bf2f(u16 h) {
  return __builtin_bit_cast(float, (u32)h << 16);
}

// async global->LDS, 16B per lane. LDS dest = wave-uniform base + lane*16.
__device__ __forceinline__ void async_load16(const u16* g, u16* l) {
  __builtin_amdgcn_global_load_lds(
      (const __attribute__((address_space(1))) void*)g,
      (__attribute__((address_space(3))) void*)l, 16, 0, 0);
}

// ---------------------------------------------------------------------------
// f32 -> bf16 elementwise convert. n multiple of 2048. 8 elems/thread.
// ---------------------------------------------------------------------------
__global__ void cvt_kernel(const float* __restrict__ src, u16* __restrict__ dst,
                           int n) {
  const int i = (blockIdx.x * 256 + threadIdx.x) * 8;
  if (i >= n) return;
  const floatx4 a = *(const floatx4*)(src + i);
  const floatx4 b = *(const floatx4*)(src + i + 4);
  short8 h;
  h[0] = (short)f2bf(a[0]); h[1] = (short)f2bf(a[1]);
  h[2] = (short)f2bf(a[2]); h[3] = (short)f2bf(a[3]);
  h[4] = (short)f2bf(b[0]); h[5] = (short)f2bf(b[1]);
  h[6] = (short)f2bf(b[2]); h[7] = (short)f2bf(b[3]);
  *(short8*)(dst + i) = h;
}

// ---------------------------------------------------------------------------
// bf16 GEMM: C = A(Mx2048) * W(2048x2048)^T + bias, all-bf16 inputs.
// global_load_lds(16B) staging, unpadded LDS with XOR-of-row chunk swizzle.
// qkv=1: blockIdx.x in [0,48): which = x>>4 selects {Q,K,V} weight/output.
//   mode 0/1: write bf16 (b,h,s,d); mode 2: write bf16 (b,h,d,s) [V^T].
// qkv=0: mode 3: write f32 MxN (O-projection).
// 128x128 tile, BK=64, 4 waves, 4x4 16x16x32 MFMA per wave.
// ---------------------------------------------------------------------------
__global__ __launch_bounds__(256, 2) void gemm_async(
    const u16* __restrict__ A, const u16* __restrict__ W0,
    const u16* __restrict__ W1, const u16* __restrict__ W2,
    const float* __restrict__ b0, const float* __restrict__ b1,
    const float* __restrict__ b2, void* __restrict__ C0, void* __restrict__ C1,
    void* __restrict__ C2, const int qkv) {
  __shared__ u16 As[128 * 64];
  __shared__ u16 Bs[128 * 64];
  const int tid = threadIdx.x;
  const int wave = tid >> 6, lane = tid & 63;
  const int lr = lane & 15, lg = lane >> 4;
  const int m0 = blockIdx.y * 128;
  const int wm = (wave & 1) * 64, wn = (wave >> 1) * 64;

  int n0, mode;
  const u16* W;
  const float* bias;
  void* C;
  if (qkv) {
    const int which = blockIdx.x >> 4;
    n0 = (blockIdx.x & 15) * 128;
    W = which == 0 ? W0 : which == 1 ? W1 : W2;
    bias = which == 0 ? b0 : which == 1 ? b1 : b2;
    C = which == 0 ? C0 : which == 1 ? C1 : C2;
    mode = which;
  } else {
    n0 = blockIdx.x * 128;
    W = W0; bias = b0; C = C0; mode = 3;
  }

  floatx4 acc[4][4];
#pragma unroll
  for (int i = 0; i < 4; ++i)
#pragma unroll
    for (int j = 0; j < 4; ++j) {
      floatx4 z = {0.f, 0.f, 0.f, 0.f};
      acc[i][j] = z;
    }

  for (int kt = 0; kt < D_MODEL; kt += 64) {
    // stage A and W tiles: 128 rows x 8 chunks (16B) each, swizzled source.
#pragma unroll
    for (int p = 0; p < 4; ++p) {
      const int s = p * 256 + tid;
      const int row = s >> 3, c = s & 7;
      const int g = c ^ (row & 7);  // source chunk for this LDS slot
      async_load16(A + (size_t)(m0 + row) * D_MODEL + kt + g * 8,
                   &As[(p * 256 + wave * 64) * 8]);
    }
#pragma unroll
    for (int p = 0; p < 4; ++p) {
      const int s = p * 256 + tid;
      const int row = s >> 3, c = s & 7;
      const int g = c ^ (row & 7);
      async_load16(W + (size_t)(n0 + row) * D_MODEL + kt + g * 8,
                   &Bs[(p * 256 + wave * 64) * 8]);
    }
    __syncthreads();

#pragma unroll
    for (int ks = 0; ks < 2; ++ks) {
      short8 af[4], bfr[4];
      const int ch = (ks * 4 + lg) ^ (lr & 7);  // swizzled chunk to read
#pragma unroll
      for (int i = 0; i < 4; ++i)
        af[i] = *(const short8*)&As[(wm + 16 * i + lr) * 64 + ch * 8];
#pragma unroll
      for (int j = 0; j < 4; ++j)
        bfr[j] = *(const short8*)&Bs[(wn + 16 * j + lr) * 64 + ch * 8];
#pragma unroll
      for (int i = 0; i < 4; ++i)
#pragma unroll
        for (int j = 0; j < 4; ++j)
          acc[i][j] = __builtin_amdgcn_mfma_f32_16x16x32_bf16(af[i], bfr[j],
                                                              acc[i][j], 0, 0, 0);
    }
    __syncthreads();
  }

  // epilogue
  float bj[4];
  int ncol[4];
#pragma unroll
  for (int j = 0; j < 4; ++j) {
    ncol[j] = n0 + wn + 16 * j + lr;
    bj[j] = bias[ncol[j]];
  }

  if (mode == 3) {
    float* Cf = (float*)C;
#pragma unroll
    for (int i = 0; i < 4; ++i)
#pragma unroll
      for (int r = 0; r < 4; ++r) {
        const int m = m0 + wm + 16 * i + lg * 4 + r;
#pragma unroll
        for (int j = 0; j < 4; ++j)
          Cf[(size_t)m * D_MODEL + ncol[j]] = acc[i][j][r] + bj[j];
      }
  } else if (mode == 2) {
    u16* Ch = (u16*)C;
#pragma unroll
    for (int i = 0; i < 4; ++i)
#pragma unroll
      for (int r = 0; r < 4; ++r) {
        const int m = m0 + wm + 16 * i + lg * 4 + r;
        const int b = m >> 11, s = m & (SEQ - 1);
#pragma unroll
        for (int j = 0; j < 4; ++j) {
          const int h = ncol[j] >> 7, d = ncol[j] & (DH - 1);
          Ch[((size_t)((b * NH + h) * DH + d)) * SEQ + s] =
              f2bf(acc[i][j][r] + bj[j]);
        }
      }
  } else {
    u16* Ch = (u16*)C;
#pragma unroll
    for (int i = 0; i < 4; ++i)
#pragma unroll
      for (int r = 0; r < 4; ++r) {
        const int m = m0 + wm + 16 * i + lg * 4 + r;
        const int b = m >> 11, s = m & (SEQ - 1);
#pragma unroll
        for (int j = 0; j < 4; ++j) {
          const int h = ncol[j] >> 7, d = ncol[j] & (DH - 1);
          Ch[((size_t)((b * NH + h) * SEQ + s)) * DH + d] =
              f2bf(acc[i][j][r] + bj[j]);
        }
      }
  }
}

// ---------------------------------------------------------------------------
// Round-1 fallback GEMM (f32 sources, VALU convert staging) — used only if
// ws_size is too small for the bf16-staged path.
// ---------------------------------------------------------------------------
template <int ABF16>
__global__ __launch_bounds__(256, 2) void gemm_kernel(
    const void* __restrict__ Aptr, const float* __restrict__ W,
    const float* __restrict__ bias, void* __restrict__ Cptr, const int mode) {
  __shared__ u16 As[128 * 72];
  __shared__ u16 Bs[128 * 72];
  const int tid = threadIdx.x;
  const int wave = tid >> 6, lane = tid & 63;
  const int lr = lane & 15, lg = lane >> 4;
  const int m0 = blockIdx.y * 128, n0 = blockIdx.x * 128;
  const int wm = (wave & 1) * 64, wn = (wave >> 1) * 64;

  floatx4 acc[4][4];
#pragma unroll
  for (int i = 0; i < 4; ++i)
#pragma unroll
    for (int j = 0; j < 4; ++j) {
      floatx4 z = {0.f, 0.f, 0.f, 0.f};
      acc[i][j] = z;
    }

  for (int kt = 0; kt < D_MODEL; kt += 64) {
    if (ABF16) {
      const u16* A = (const u16*)Aptr;
      const int row0 = tid >> 3, c8 = (tid & 7) * 8;
#pragma unroll
      for (int p = 0; p < 4; ++p) {
        const int row = row0 + p * 32;
        *(short8*)&As[row * 72 + c8] =
            *(const short8*)(A + (size_t)(m0 + row) * D_MODEL + kt + c8);
      }
    } else {
      const float* A = (const float*)Aptr;
      const int row0 = tid >> 4, c4 = (tid & 15) * 4;
#pragma unroll
      for (int p = 0; p < 8; ++p) {
        const int row = row0 + p * 16;
        const floatx4 v =
            *(const floatx4*)(A + (size_t)(m0 + row) * D_MODEL + kt + c4);
        ushort4v h;
        h[0] = f2bf(v[0]); h[1] = f2bf(v[1]); h[2] = f2bf(v[2]); h[3] = f2bf(v[3]);
        *(ushort4v*)&As[row * 72 + c4] = h;
      }
    }
    {
      const int row0 = tid >> 4, c4 = (tid & 15) * 4;
#pragma unroll
      for (int p = 0; p < 8; ++p) {
        const int row = row0 + p * 16;
        const floatx4 v =
            *(const floatx4*)(W + (size_t)(n0 + row) * D_MODEL + kt + c4);
        ushort4v h;
        h[0] = f2bf(v[0]); h[1] = f2bf(v[1]); h[2] = f2bf(v[2]); h[3] = f2bf(v[3]);
        *(ushort4v*)&Bs[row * 72 + c4] = h;
      }
    }
    __syncthreads();
#pragma unroll
    for (int ks = 0; ks < 2; ++ks) {
      short8 af[4], bfr[4];
#pragma unroll
      for (int i = 0; i < 4; ++i)
        af[i] = *(const short8*)&As[(wm + 16 * i + lr) * 72 + ks * 32 + lg * 8];
#pragma unroll
      for (int j = 0; j < 4; ++j)
        bfr[j] = *(const short8*)&Bs[(wn + 16 * j + lr) * 72 + ks * 32 + lg * 8];
#pragma unroll
      for (int i = 0; i < 4; ++i)
#pragma unroll
        for (int j = 0; j < 4; ++j)
          acc[i][j] = __builtin_amdgcn_mfma_f32_16x16x32_bf16(af[i], bfr[j],
                                                              acc[i][j], 0, 0, 0);
    }
    __syncthreads();
  }

  float bj[4];
  int ncol[4];
#pragma unroll
  for (int j = 0; j < 4; ++j) {
    ncol[j] = n0 + wn + 16 * j + lr;
    bj[j] = bias[ncol[j]];
  }

  if (mode == 3) {
    float* C = (float*)Cptr;
#pragma unroll
    for (int i = 0; i < 4; ++i)
#pragma unroll
      for (int r = 0; r < 4; ++r) {
        const int m = m0 + wm + 16 * i + lg * 4 + r;
#pragma unroll
        for (int j = 0; j < 4; ++j)
          C[(size_t)m * D_MODEL + ncol[j]] = acc[i][j][r] + bj[j];
      }
  } else if (mode == 2) {
    u16* C = (u16*)Cptr;
#pragma unroll
    for (int i = 0; i < 4; ++i)
#pragma unroll
      for (int r = 0; r < 4; ++r) {
        const int m = m0 + wm + 16 * i + lg * 4 + r;
        const int b = m >> 11, s = m & (SEQ - 1);
#pragma unroll
        for (int j = 0; j < 4; ++j) {
          const int h = ncol[j] >> 7, d = ncol[j] & (DH - 1);
          C[((size_t)((b * NH + h) * DH + d)) * SEQ + s] = f2bf(acc[i][j][r] + bj[j]);
        }
      }
  } else {
    u16* C = (u16*)Cptr;
#pragma unroll
    for (int i = 0; i < 4; ++i)
#pragma unroll
      for (int r = 0; r < 4; ++r) {
        const int m = m0 + wm + 16 * i + lg * 4 + r;
        const int b = m >> 11, s = m & (SEQ - 1);
#pragma unroll
        for (int j = 0; j < 4; ++j) {
          const int h = ncol[j] >> 7, d = ncol[j] & (DH - 1);
          C[((size_t)((b * NH + h) * SEQ + s)) * DH + d] = f2bf(acc[i][j][r] + bj[j]);
        }
      }
  }
}

// ---------------------------------------------------------------------------
// RoPE in-place on bf16 Q and K, layout (b,h,s,d).
// ---------------------------------------------------------------------------
__global__ void rope_kernel(u16* __restrict__ Q, u16* __restrict__ K) {
  const int idx = blockIdx.x * blockDim.x + threadIdx.x;
  const int p = idx & 63;
  const int s = (idx >> 6) & (SEQ - 1);
  const int bh = idx >> 17;
  if (bh >= NBH) return;
  const float freq = exp2f(-(float)p * (13.287712379549449f / 64.0f));
  const float ang = (float)s * freq;
  float sn, cs;
  sincosf(ang, &sn, &cs);
  const size_t base = ((size_t)bh * SEQ + s) * DH + 2 * p;
  {
    const u32 qq = *(const u32*)(Q + base);
    const float x1 = bf2f((u16)(qq & 0xffffu)), x2 = bf2f((u16)(qq >> 16));
    *(u32*)(Q + base) =
        (u32)f2bf(x1 * cs - x2 * sn) | ((u32)f2bf(x1 * sn + x2 * cs) << 16);
  }
  {
    const u32 kk = *(const u32*)(K + base);
    const float x1 = bf2f((u16)(kk & 0xffffu)), x2 = bf2f((u16)(kk >> 16));
    *(u32*)(K + base) =
        (u32)f2bf(x1 * cs - x2 * sn) | ((u32)f2bf(x1 * sn + x2 * cs) << 16);
  }
}

// ---------------------------------------------------------------------------
// Flash attention, causal (unchanged from round 1 — correct, ~65 us).
// ---------------------------------------------------------------------------
__global__ __launch_bounds__(256, 2) void attn_kernel(
    const u16* __restrict__ Q, const u16* __restrict__ K,
    const u16* __restrict__ Vt, u16* __restrict__ Oflat) {
  __shared__ u16 Ks[64 * 136];
  __shared__ u16 Vts[128 * 72];
  __shared__ u16 Ps[4 * 32 * 72];
  const int tid = threadIdx.x;
  const int wave = tid >> 6, lane = tid & 63;
  const int lr = lane & 15, lg = lane >> 4;
  const int qt = blockIdx.x, bh = blockIdx.y;
  const size_t qk0 = (size_t)bh * SEQ * DH;
  const int q0 = qt * 128 + wave * 32;
  const float scale = 0.08838834764831845f;
  const float L2E = 1.4426950408889634f;

  short8 qf[2][4];
#pragma unroll
  for (int i = 0; i < 2; ++i)
#pragma unroll
    for (int kb = 0; kb < 4; ++kb)
      qf[i][kb] = *(const short8*)(Q + qk0 + (size_t)(q0 + 16 * i + lr) * DH +
                                   kb * 32 + lg * 8);

  floatx4 o[2][8];
#pragma unroll
  for (int i = 0; i < 2; ++i)
#pragma unroll
    for (int jd = 0; jd < 8; ++jd) {
      floatx4 z = {0.f, 0.f, 0.f, 0.f};
      o[i][jd] = z;
    }
  float mrun[2][4], lrun[2][4];
#pragma unroll
  for (int i = 0; i < 2; ++i)
#pragma unroll
    for (int r = 0; r < 4; ++r) {
      mrun[i][r] = -1e38f;
      lrun[i][r] = 0.f;
    }

  u16* myP = &Ps[wave * 32 * 72];
  const int nkt = 2 * qt + 2;
  for (int kt = 0; kt < nkt; ++kt) {
    {
      const int row0 = tid >> 4, c8 = (tid & 15) * 8;
#pragma unroll
      for (int p = 0; p < 4; ++p) {
        const int r_ = row0 + p * 16;
        *(short8*)&Ks[r_ * 136 + c8] =
            *(const short8*)(K + qk0 + (size_t)(kt * 64 + r_) * DH + c8);
      }
    }
    {
      const int row0 = tid >> 3, c8 = (tid & 7) * 8;
#pragma unroll
      for (int p = 0; p < 4; ++p) {
        const int r_ = row0 + p * 32;
        *(short8*)&Vts[r_ * 72 + c8] = *(const short8*)(
            Vt + (size_t)bh * DH * SEQ + (size_t)r_ * SEQ + kt * 64 + c8);
      }
    }
    __syncthreads();

    floatx4 sacc[2][4];
#pragma unroll
    for (int i = 0; i < 2; ++i)
#pragma unroll
      for (int j = 0; j < 4; ++j) {
        floatx4 z = {0.f, 0.f, 0.f, 0.f};
        sacc[i][j] = z;
      }
#pragma unroll
    for (int kb = 0; kb < 4; ++kb) {
      short8 kf[4];
#pragma unroll
      for (int j = 0; j < 4; ++j)
        kf[j] = *(const short8*)&Ks[(16 * j + lr) * 136 + kb * 32 + lg * 8];
#pragma unroll
      for (int i = 0; i < 2; ++i)
#pragma unroll
        for (int j = 0; j < 4; ++j)
          sacc[i][j] = __builtin_amdgcn_mfma_f32_16x16x32_bf16(qf[i][kb], kf[j],
                                                               sacc[i][j], 0, 0, 0);
    }

    const bool mask_tile = (kt >= 2 * qt);
#pragma unroll
    for (int i = 0; i < 2; ++i)
#pragma unroll
      for (int j = 0; j < 4; ++j)
#pragma unroll
        for (int r = 0; r < 4; ++r) {
          float v = sacc[i][j][r] * scale;
          if (mask_tile) {
            const int kpos = kt * 64 + 16 * j + lr;
            const int qpos = q0 + 16 * i + lg * 4 + r;
            if (kpos > qpos) v = -1e30f;
          }
          sacc[i][j][r] = v;
        }

    float mnew[2][4], alpha[2][4], rs[2][4];
#pragma unroll
    for (int i = 0; i < 2; ++i)
#pragma unroll
      for (int r = 0; r < 4; ++r) {
        float mx = fmaxf(fmaxf(sacc[i][0][r], sacc[i][1][r]),
                         fmaxf(sacc[i][2][r], sacc[i][3][r]));
#pragma unroll
        for (int d = 1; d < 16; d <<= 1) mx = fmaxf(mx, __shfl_xor(mx, d, 64));
        const float mn = fmaxf(mrun[i][r], mx);
        mnew[i][r] = mn;
        alpha[i][r] = exp2f((mrun[i][r] - mn) * L2E);
        mrun[i][r] = mn;
        rs[i][r] = 0.f;
      }

#pragma unroll
    for (int i = 0; i < 2; ++i)
#pragma unroll
      for (int j = 0; j < 4; ++j)
#pragma unroll
        for (int r = 0; r < 4; ++r) {
          const float pv = exp2f((sacc[i][j][r] - mnew[i][r]) * L2E);
          rs[i][r] += pv;
          myP[(16 * i + lg * 4 + r) * 72 + 16 * j + lr] = f2bf(pv);
        }

#pragma unroll
    for (int i = 0; i < 2; ++i)
#pragma unroll
      for (int r = 0; r < 4; ++r) {
        float s_ = rs[i][r];
#pragma unroll
        for (int d = 1; d < 16; d <<= 1) s_ += __shfl_xor(s_, d, 64);
        lrun[i][r] = lrun[i][r] * alpha[i][r] + s_;
      }

#pragma unroll
    for (int i = 0; i < 2; ++i)
#pragma unroll
      for (int jd = 0; jd < 8; ++jd)
#pragma unroll
        for (int r = 0; r < 4; ++r) o[i][jd][r] *= alpha[i][r];

    asm volatile("s_waitcnt lgkmcnt(0)" ::: "memory");

#pragma unroll
    for (int kb = 0; kb < 2; ++kb) {
      short8 pf[2];
#pragma unroll
      for (int i = 0; i < 2; ++i)
        pf[i] = *(const short8*)&myP[(16 * i + lr) * 72 + kb * 32 + lg * 8];
#pragma unroll
      for (int jd = 0; jd < 8; ++jd) {
        const short8 vf =
            *(const short8*)&Vts[(16 * jd + lr) * 72 + kb * 32 + lg * 8];
#pragma unroll
        for (int i = 0; i < 2; ++i)
          o[i][jd] = __builtin_amdgcn_mfma_f32_16x16x32_bf16(pf[i], vf, o[i][jd],
                                                             0, 0, 0);
      }
    }
    __syncthreads();
  }

  const int b = bh >> 4, h = bh & (NH - 1);
#pragma unroll
  for (int i = 0; i < 2; ++i)
#pragma unroll
    for (int r = 0; r < 4; ++r) {
      const int qpos = q0 + 16 * i + lg * 4 + r;
      const float inv = 1.0f / lrun[i][r];
      u16* dst = Oflat + ((size_t)(b * SEQ + qpos)) * D_MODEL + h * DH;
#pragma unroll
      for (int jd = 0; jd < 8; ++jd) dst[16 * jd + lr] = f2bf(o[i][jd][r] * inv);
    }
}

// ---------------------------------------------------------------------------
extern "C" void kernel_launch(void* const* d_in, const int* in_sizes, int n_in,
                              void* d_out, int out_size, void* d_ws,
                              size_t ws_size, hipStream_t stream) {
  const float* x = (const float*)d_in[0];
  const float* Wq = (const float*)d_in[1];
  const float* bq = (const float*)d_in[2];
  const float* Wk = (const float*)d_in[3];
  const float* bk = (const float*)d_in[4];
  const float* Wv = (const float*)d_in[5];
  const float* bv = (const float*)d_in[6];
  const float* Wo = (const float*)d_in[7];
  const float* bo = (const float*)d_in[8];
  float* out = (float*)d_out;

  const size_t E = (size_t)NBH * SEQ * DH;      // 8.39M elems (x / q / k / vt)
  const size_t WE = (size_t)D_MODEL * D_MODEL;  // 4.19M elems (weights)
  const size_t need = (4 * E + 3 * WE) * sizeof(u16);  // 92.3 MB

  const dim3 gb(256);

  if (ws_size >= need) {
    // layout: xb(=aflat later) | wqb | wkb | wvb | q(=wob later) | k | vt
    u16* xb = (u16*)d_ws;
    u16* wqb = xb + E;
    u16* wkb = wqb + WE;
    u16* wvb = wkb + WE;
    u16* q = wvb + WE;
    u16* k = q + E;
    u16* vt = k + E;
    u16* aflat = xb;  // xb dead after QKV GEMM
    u16* wob = q;     // q dead after attention

    cvt_kernel<<<dim3((int)(E / 2048)), gb, 0, stream>>>(x, xb, (int)E);
    cvt_kernel<<<dim3((int)(WE / 2048)), gb, 0, stream>>>(Wq, wqb, (int)WE);
    cvt_kernel<<<dim3((int)(WE / 2048)), gb, 0, stream>>>(Wk, wkb, (int)WE);
    cvt_kernel<<<dim3((int)(WE / 2048)), gb, 0, stream>>>(Wv, wvb, (int)WE);

    gemm_async<<<dim3(48, 32), gb, 0, stream>>>(xb, wqb, wkb, wvb, bq, bk, bv,
                                                q, k, vt, 1);
    rope_kernel<<<dim3((NBH * SEQ * (DH / 2)) / 256), gb, 0, stream>>>(q, k);
    attn_kernel<<<dim3(SEQ / 128, NBH), gb, 0, stream>>>(q, k, vt, aflat);
    cvt_kernel<<<dim3((int)(WE / 2048)), gb, 0, stream>>>(Wo, wob, (int)WE);
    gemm_async<<<dim3(16, 32), gb, 0, stream>>>(aflat, wob, nullptr, nullptr,
                                                bo, nullptr, nullptr, out,
                                                nullptr, nullptr, 0);
  } else {
    // round-1 fallback (64 MB ws)
    u16* q = (u16*)d_ws;
    u16* k = q + E;
    u16* vt = k + E;
    u16* aflat = vt + E;
    const dim3 gg(D_MODEL / 128, (2 * SEQ) / 128);
    gemm_kernel<0><<<gg, gb, 0, stream>>>(x, Wq, bq, q, 0);
    gemm_kernel<0><<<gg, gb, 0, stream>>>(x, Wk, bk, k, 1);
    gemm_kernel<0><<<gg, gb, 0, stream>>>(x, Wv, bv, vt, 2);
    rope_kernel<<<dim3((NBH * SEQ * (DH / 2)) / 256), dim3(256), 0, stream>>>(q, k);
    attn_kernel<<<dim3(SEQ / 128, NBH), gb, 0, stream>>>(q, k, vt, aflat);
    gemm_kernel<1><<<gg, gb, 0, stream>>>(aflat, Wo, bo, out, 3);
  }
}

// Round 3
// 416.839 us; speedup vs baseline: 2.7058x; 1.2457x over previous
//
#include <hip/hip_runtime.h>
#include <math.h>

#define D_MODEL 2048
#define NH 16
#define DH 128
#define SEQ 2048
#define NBH 32  // batch * heads

typedef unsigned short u16;
typedef unsigned int u32;
typedef __attribute__((ext_vector_type(8))) short short8;
typedef __attribute__((ext_vector_type(4))) float floatx4;
typedef __attribute__((ext_vector_type(4))) unsigned short ushort4v;

__device__ __forceinline__ u16 f2bf(float f) {
  u32 u = __builtin_bit_cast(u32, f);
  return (u16)((u + 0x8000u) >> 16);
}
__device__ __forceinline__ float bf2f(u16 h) {
  return __builtin_bit_cast(float, (u32)h << 16);
}

// async global->LDS, 16B per lane. LDS dest = wave-uniform base + lane*16.
__device__ __forceinline__ void async_load16(const u16* g, u16* l) {
  __builtin_amdgcn_global_load_lds(
      (const __attribute__((address_space(1))) void*)g,
      (__attribute__((address_space(3))) void*)l, 16, 0, 0);
}

// DPP move within the 16-lane row (VALU pipe — no LDS latency).
template <int CTRL>
__device__ __forceinline__ float dpp_mov(float x) {
  return __builtin_bit_cast(
      float, __builtin_amdgcn_update_dpp(0, __builtin_bit_cast(int, x), CTRL,
                                         0xf, 0xf, false));
}
// full 16-lane reductions via row_ror 1/2/4/8 (0x121/0x122/0x124/0x128)
__device__ __forceinline__ float rmax16(float x) {
  x = fmaxf(x, dpp_mov<0x121>(x));
  x = fmaxf(x, dpp_mov<0x122>(x));
  x = fmaxf(x, dpp_mov<0x124>(x));
  x = fmaxf(x, dpp_mov<0x128>(x));
  return x;
}
__device__ __forceinline__ float radd16(float x) {
  x += dpp_mov<0x121>(x);
  x += dpp_mov<0x122>(x);
  x += dpp_mov<0x124>(x);
  x += dpp_mov<0x128>(x);
  return x;
}

// ---------------------------------------------------------------------------
// f32 -> bf16 elementwise convert. n multiple of 2048. 8 elems/thread.
// ---------------------------------------------------------------------------
__global__ void cvt_kernel(const float* __restrict__ src, u16* __restrict__ dst,
                           int n) {
  const int i = (blockIdx.x * 256 + threadIdx.x) * 8;
  if (i >= n) return;
  const floatx4 a = *(const floatx4*)(src + i);
  const floatx4 b = *(const floatx4*)(src + i + 4);
  short8 h;
  h[0] = (short)f2bf(a[0]); h[1] = (short)f2bf(a[1]);
  h[2] = (short)f2bf(a[2]); h[3] = (short)f2bf(a[3]);
  h[4] = (short)f2bf(b[0]); h[5] = (short)f2bf(b[1]);
  h[6] = (short)f2bf(b[2]); h[7] = (short)f2bf(b[3]);
  *(short8*)(dst + i) = h;
}

// ---------------------------------------------------------------------------
// bf16 GEMM (unchanged from round 2): global_load_lds staging, XOR swizzle.
// ---------------------------------------------------------------------------
__global__ __launch_bounds__(256, 2) void gemm_async(
    const u16* __restrict__ A, const u16* __restrict__ W0,
    const u16* __restrict__ W1, const u16* __restrict__ W2,
    const float* __restrict__ b0, const float* __restrict__ b1,
    const float* __restrict__ b2, void* __restrict__ C0, void* __restrict__ C1,
    void* __restrict__ C2, const int qkv) {
  __shared__ u16 As[128 * 64];
  __shared__ u16 Bs[128 * 64];
  const int tid = threadIdx.x;
  const int wave = tid >> 6, lane = tid & 63;
  const int lr = lane & 15, lg = lane >> 4;
  const int m0 = blockIdx.y * 128;
  const int wm = (wave & 1) * 64, wn = (wave >> 1) * 64;

  int n0, mode;
  const u16* W;
  const float* bias;
  void* C;
  if (qkv) {
    const int which = blockIdx.x >> 4;
    n0 = (blockIdx.x & 15) * 128;
    W = which == 0 ? W0 : which == 1 ? W1 : W2;
    bias = which == 0 ? b0 : which == 1 ? b1 : b2;
    C = which == 0 ? C0 : which == 1 ? C1 : C2;
    mode = which;
  } else {
    n0 = blockIdx.x * 128;
    W = W0; bias = b0; C = C0; mode = 3;
  }

  floatx4 acc[4][4];
#pragma unroll
  for (int i = 0; i < 4; ++i)
#pragma unroll
    for (int j = 0; j < 4; ++j) {
      floatx4 z = {0.f, 0.f, 0.f, 0.f};
      acc[i][j] = z;
    }

  for (int kt = 0; kt < D_MODEL; kt += 64) {
#pragma unroll
    for (int p = 0; p < 4; ++p) {
      const int s = p * 256 + tid;
      const int row = s >> 3, c = s & 7;
      const int g = c ^ (row & 7);
      async_load16(A + (size_t)(m0 + row) * D_MODEL + kt + g * 8,
                   &As[(p * 256 + wave * 64) * 8]);
    }
#pragma unroll
    for (int p = 0; p < 4; ++p) {
      const int s = p * 256 + tid;
      const int row = s >> 3, c = s & 7;
      const int g = c ^ (row & 7);
      async_load16(W + (size_t)(n0 + row) * D_MODEL + kt + g * 8,
                   &Bs[(p * 256 + wave * 64) * 8]);
    }
    __syncthreads();

#pragma unroll
    for (int ks = 0; ks < 2; ++ks) {
      short8 af[4], bfr[4];
      const int ch = (ks * 4 + lg) ^ (lr & 7);
#pragma unroll
      for (int i = 0; i < 4; ++i)
        af[i] = *(const short8*)&As[(wm + 16 * i + lr) * 64 + ch * 8];
#pragma unroll
      for (int j = 0; j < 4; ++j)
        bfr[j] = *(const short8*)&Bs[(wn + 16 * j + lr) * 64 + ch * 8];
#pragma unroll
      for (int i = 0; i < 4; ++i)
#pragma unroll
        for (int j = 0; j < 4; ++j)
          acc[i][j] = __builtin_amdgcn_mfma_f32_16x16x32_bf16(af[i], bfr[j],
                                                              acc[i][j], 0, 0, 0);
    }
    __syncthreads();
  }

  float bj[4];
  int ncol[4];
#pragma unroll
  for (int j = 0; j < 4; ++j) {
    ncol[j] = n0 + wn + 16 * j + lr;
    bj[j] = bias[ncol[j]];
  }

  if (mode == 3) {
    float* Cf = (float*)C;
#pragma unroll
    for (int i = 0; i < 4; ++i)
#pragma unroll
      for (int r = 0; r < 4; ++r) {
        const int m = m0 + wm + 16 * i + lg * 4 + r;
#pragma unroll
        for (int j = 0; j < 4; ++j)
          Cf[(size_t)m * D_MODEL + ncol[j]] = acc[i][j][r] + bj[j];
      }
  } else if (mode == 2) {
    u16* Ch = (u16*)C;
#pragma unroll
    for (int i = 0; i < 4; ++i)
#pragma unroll
      for (int r = 0; r < 4; ++r) {
        const int m = m0 + wm + 16 * i + lg * 4 + r;
        const int b = m >> 11, s = m & (SEQ - 1);
#pragma unroll
        for (int j = 0; j < 4; ++j) {
          const int h = ncol[j] >> 7, d = ncol[j] & (DH - 1);
          Ch[((size_t)((b * NH + h) * DH + d)) * SEQ + s] =
              f2bf(acc[i][j][r] + bj[j]);
        }
      }
  } else {
    u16* Ch = (u16*)C;
#pragma unroll
    for (int i = 0; i < 4; ++i)
#pragma unroll
      for (int r = 0; r < 4; ++r) {
        const int m = m0 + wm + 16 * i + lg * 4 + r;
        const int b = m >> 11, s = m & (SEQ - 1);
#pragma unroll
        for (int j = 0; j < 4; ++j) {
          const int h = ncol[j] >> 7, d = ncol[j] & (DH - 1);
          Ch[((size_t)((b * NH + h) * SEQ + s)) * DH + d] =
              f2bf(acc[i][j][r] + bj[j]);
        }
      }
  }
}

// ---------------------------------------------------------------------------
// RoPE in-place on bf16 Q and K, layout (b,h,s,d).
// ---------------------------------------------------------------------------
__global__ void rope_kernel(u16* __restrict__ Q, u16* __restrict__ K) {
  const int idx = blockIdx.x * blockDim.x + threadIdx.x;
  const int p = idx & 63;
  const int s = (idx >> 6) & (SEQ - 1);
  const int bh = idx >> 17;
  if (bh >= NBH) return;
  const float freq = exp2f(-(float)p * (13.287712379549449f / 64.0f));
  const float ang = (float)s * freq;
  float sn, cs;
  sincosf(ang, &sn, &cs);
  const size_t base = ((size_t)bh * SEQ + s) * DH + 2 * p;
  {
    const u32 qq = *(const u32*)(Q + base);
    const float x1 = bf2f((u16)(qq & 0xffffu)), x2 = bf2f((u16)(qq >> 16));
    *(u32*)(Q + base) =
        (u32)f2bf(x1 * cs - x2 * sn) | ((u32)f2bf(x1 * sn + x2 * cs) << 16);
  }
  {
    const u32 kk = *(const u32*)(K + base);
    const float x1 = bf2f((u16)(kk & 0xffffu)), x2 = bf2f((u16)(kk >> 16));
    *(u32*)(K + base) =
        (u32)f2bf(x1 * cs - x2 * sn) | ((u32)f2bf(x1 * sn + x2 * cs) << 16);
  }
}

// ---------------------------------------------------------------------------
// Flash attention, causal. Changes this round:
//  * complementary qt remap: resident block pairs sum to 34 k-tiles (balance)
//  * DPP row_ror reductions for max/sum (VALU pipe, no ds_swizzle chains)
//  * global_load_lds(16B) staging of K & Vt, XOR chunk swizzle, unpadded LDS
// ---------------------------------------------------------------------------
__global__ __launch_bounds__(256, 2) void attn_kernel(
    const u16* __restrict__ Q, const u16* __restrict__ K,
    const u16* __restrict__ Vt, u16* __restrict__ Oflat) {
  __shared__ u16 Ks[64 * 128];    // 16 KB, swizzled chunks
  __shared__ u16 Vts[128 * 64];   // 16 KB, swizzled chunks
  __shared__ u16 Ps[4 * 32 * 72]; // 18 KB, padded (stride 72)
  const int tid = threadIdx.x;
  const int wave = tid >> 6, lane = tid & 63;
  const int lr = lane & 15, lg = lane >> 4;
  // complementary mapping: blocks (x, y) and (x, y+16) have qt summing to 15
  const int bh = blockIdx.y;
  const int qt = (blockIdx.y < 16) ? blockIdx.x : (15 - blockIdx.x);
  const size_t qk0 = (size_t)bh * SEQ * DH;
  const int q0 = qt * 128 + wave * 32;
  const float scale = 0.08838834764831845f;  // 1/sqrt(128)
  const float L2E = 1.4426950408889634f;

  short8 qf[2][4];
#pragma unroll
  for (int i = 0; i < 2; ++i)
#pragma unroll
    for (int kb = 0; kb < 4; ++kb)
      qf[i][kb] = *(const short8*)(Q + qk0 + (size_t)(q0 + 16 * i + lr) * DH +
                                   kb * 32 + lg * 8);

  floatx4 o[2][8];
#pragma unroll
  for (int i = 0; i < 2; ++i)
#pragma unroll
    for (int jd = 0; jd < 8; ++jd) {
      floatx4 z = {0.f, 0.f, 0.f, 0.f};
      o[i][jd] = z;
    }
  float mrun[2][4], lrun[2][4];
#pragma unroll
  for (int i = 0; i < 2; ++i)
#pragma unroll
    for (int r = 0; r < 4; ++r) {
      mrun[i][r] = -1e38f;
      lrun[i][r] = 0.f;
    }

  u16* myP = &Ps[wave * 32 * 72];
  const int nkt = 2 * qt + 2;
  for (int kt = 0; kt < nkt; ++kt) {
    // stage K tile: 64 rows x 16 chunks (8 u16 each), physical chunk = c ^ (row&15)
#pragma unroll
    for (int p = 0; p < 4; ++p) {
      const int s = p * 256 + tid;
      const int row = s >> 4, c = s & 15;
      const int g = c ^ (row & 15);
      async_load16(K + qk0 + (size_t)(kt * 64 + row) * DH + g * 8,
                   &Ks[(p * 256 + wave * 64) * 8]);
    }
    // stage Vt tile: 128 rows x 8 chunks, physical chunk = c ^ (row&7)
#pragma unroll
    for (int p = 0; p < 4; ++p) {
      const int s = p * 256 + tid;
      const int row = s >> 3, c = s & 7;
      const int g = c ^ (row & 7);
      async_load16(Vt + (size_t)bh * DH * SEQ + (size_t)row * SEQ + kt * 64 + g * 8,
                   &Vts[(p * 256 + wave * 64) * 8]);
    }
    __syncthreads();

    // S = Q K^T strip: 32 rows x 64 cols per wave
    floatx4 sacc[2][4];
#pragma unroll
    for (int i = 0; i < 2; ++i)
#pragma unroll
      for (int j = 0; j < 4; ++j) {
        floatx4 z = {0.f, 0.f, 0.f, 0.f};
        sacc[i][j] = z;
      }
#pragma unroll
    for (int kb = 0; kb < 4; ++kb) {
      short8 kf[4];
#pragma unroll
      for (int j = 0; j < 4; ++j)
        kf[j] = *(const short8*)&Ks[(16 * j + lr) * 128 + (((kb * 4 + lg) ^ lr)) * 8];
#pragma unroll
      for (int i = 0; i < 2; ++i)
#pragma unroll
        for (int j = 0; j < 4; ++j)
          sacc[i][j] = __builtin_amdgcn_mfma_f32_16x16x32_bf16(qf[i][kb], kf[j],
                                                               sacc[i][j], 0, 0, 0);
    }

    const bool mask_tile = (kt >= 2 * qt);
#pragma unroll
    for (int i = 0; i < 2; ++i)
#pragma unroll
      for (int j = 0; j < 4; ++j)
#pragma unroll
        for (int r = 0; r < 4; ++r) {
          float v = sacc[i][j][r] * scale;
          if (mask_tile) {
            const int kpos = kt * 64 + 16 * j + lr;
            const int qpos = q0 + 16 * i + lg * 4 + r;
            if (kpos > qpos) v = -1e30f;
          }
          sacc[i][j][r] = v;
        }

    // online softmax: DPP 16-lane reductions (rows owned by lanes sharing lg)
    float mnew[2][4], alpha[2][4], rs[2][4];
#pragma unroll
    for (int i = 0; i < 2; ++i)
#pragma unroll
      for (int r = 0; r < 4; ++r) {
        float mx = fmaxf(fmaxf(sacc[i][0][r], sacc[i][1][r]),
                         fmaxf(sacc[i][2][r], sacc[i][3][r]));
        mx = rmax16(mx);
        const float mn = fmaxf(mrun[i][r], mx);
        mnew[i][r] = mn;
        alpha[i][r] = exp2f((mrun[i][r] - mn) * L2E);
        mrun[i][r] = mn;
        rs[i][r] = 0.f;
      }

#pragma unroll
    for (int i = 0; i < 2; ++i)
#pragma unroll
      for (int j = 0; j < 4; ++j)
#pragma unroll
        for (int r = 0; r < 4; ++r) {
          const float pv = exp2f((sacc[i][j][r] - mnew[i][r]) * L2E);
          rs[i][r] += pv;
          myP[(16 * i + lg * 4 + r) * 72 + 16 * j + lr] = f2bf(pv);
        }

#pragma unroll
    for (int i = 0; i < 2; ++i)
#pragma unroll
      for (int r = 0; r < 4; ++r)
        lrun[i][r] = lrun[i][r] * alpha[i][r] + radd16(rs[i][r]);

#pragma unroll
    for (int i = 0; i < 2; ++i)
#pragma unroll
      for (int jd = 0; jd < 8; ++jd)
#pragma unroll
        for (int r = 0; r < 4; ++r) o[i][jd][r] *= alpha[i][r];

    // drain our ds_writes of P before reading them back as A-fragments
    asm volatile("s_waitcnt lgkmcnt(0)" ::: "memory");

#pragma unroll
    for (int kb = 0; kb < 2; ++kb) {
      short8 pf[2];
#pragma unroll
      for (int i = 0; i < 2; ++i)
        pf[i] = *(const short8*)&myP[(16 * i + lr) * 72 + kb * 32 + lg * 8];
#pragma unroll
      for (int jd = 0; jd < 8; ++jd) {
        const short8 vf = *(const short8*)&Vts[(16 * jd + lr) * 64 +
                                               (((kb * 4 + lg) ^ (lr & 7))) * 8];
#pragma unroll
        for (int i = 0; i < 2; ++i)
          o[i][jd] = __builtin_amdgcn_mfma_f32_16x16x32_bf16(pf[i], vf, o[i][jd],
                                                             0, 0, 0);
      }
    }
    __syncthreads();
  }

  const int b = bh >> 4, h = bh & (NH - 1);
#pragma unroll
  for (int i = 0; i < 2; ++i)
#pragma unroll
    for (int r = 0; r < 4; ++r) {
      const int qpos = q0 + 16 * i + lg * 4 + r;
      const float inv = 1.0f / lrun[i][r];
      u16* dst = Oflat + ((size_t)(b * SEQ + qpos)) * D_MODEL + h * DH;
#pragma unroll
      for (int jd = 0; jd < 8; ++jd) dst[16 * jd + lr] = f2bf(o[i][jd][r] * inv);
    }
}

// ---------------------------------------------------------------------------
// Round-1 fallback GEMM (f32 sources) — used only if ws too small.
// ---------------------------------------------------------------------------
template <int ABF16>
__global__ __launch_bounds__(256, 2) void gemm_kernel(
    const void* __restrict__ Aptr, const float* __restrict__ W,
    const float* __restrict__ bias, void* __restrict__ Cptr, const int mode) {
  __shared__ u16 As[128 * 72];
  __shared__ u16 Bs[128 * 72];
  const int tid = threadIdx.x;
  const int wave = tid >> 6, lane = tid & 63;
  const int lr = lane & 15, lg = lane >> 4;
  const int m0 = blockIdx.y * 128, n0 = blockIdx.x * 128;
  const int wm = (wave & 1) * 64, wn = (wave >> 1) * 64;

  floatx4 acc[4][4];
#pragma unroll
  for (int i = 0; i < 4; ++i)
#pragma unroll
    for (int j = 0; j < 4; ++j) {
      floatx4 z = {0.f, 0.f, 0.f, 0.f};
      acc[i][j] = z;
    }

  for (int kt = 0; kt < D_MODEL; kt += 64) {
    if (ABF16) {
      const u16* A = (const u16*)Aptr;
      const int row0 = tid >> 3, c8 = (tid & 7) * 8;
#pragma unroll
      for (int p = 0; p < 4; ++p) {
        const int row = row0 + p * 32;
        *(short8*)&As[row * 72 + c8] =
            *(const short8*)(A + (size_t)(m0 + row) * D_MODEL + kt + c8);
      }
    } else {
      const float* A = (const float*)Aptr;
      const int row0 = tid >> 4, c4 = (tid & 15) * 4;
#pragma unroll
      for (int p = 0; p < 8; ++p) {
        const int row = row0 + p * 16;
        const floatx4 v =
            *(const floatx4*)(A + (size_t)(m0 + row) * D_MODEL + kt + c4);
        ushort4v h;
        h[0] = f2bf(v[0]); h[1] = f2bf(v[1]); h[2] = f2bf(v[2]); h[3] = f2bf(v[3]);
        *(ushort4v*)&As[row * 72 + c4] = h;
      }
    }
    {
      const int row0 = tid >> 4, c4 = (tid & 15) * 4;
#pragma unroll
      for (int p = 0; p < 8; ++p) {
        const int row = row0 + p * 16;
        const floatx4 v =
            *(const floatx4*)(W + (size_t)(n0 + row) * D_MODEL + kt + c4);
        ushort4v h;
        h[0] = f2bf(v[0]); h[1] = f2bf(v[1]); h[2] = f2bf(v[2]); h[3] = f2bf(v[3]);
        *(ushort4v*)&Bs[row * 72 + c4] = h;
      }
    }
    __syncthreads();
#pragma unroll
    for (int ks = 0; ks < 2; ++ks) {
      short8 af[4], bfr[4];
#pragma unroll
      for (int i = 0; i < 4; ++i)
        af[i] = *(const short8*)&As[(wm + 16 * i + lr) * 72 + ks * 32 + lg * 8];
#pragma unroll
      for (int j = 0; j < 4; ++j)
        bfr[j] = *(const short8*)&Bs[(wn + 16 * j + lr) * 72 + ks * 32 + lg * 8];
#pragma unroll
      for (int i = 0; i < 4; ++i)
#pragma unroll
        for (int j = 0; j < 4; ++j)
          acc[i][j] = __builtin_amdgcn_mfma_f32_16x16x32_bf16(af[i], bfr[j],
                                                              acc[i][j], 0, 0, 0);
    }
    __syncthreads();
  }

  float bj[4];
  int ncol[4];
#pragma unroll
  for (int j = 0; j < 4; ++j) {
    ncol[j] = n0 + wn + 16 * j + lr;
    bj[j] = bias[ncol[j]];
  }

  if (mode == 3) {
    float* C = (float*)Cptr;
#pragma unroll
    for (int i = 0; i < 4; ++i)
#pragma unroll
      for (int r = 0; r < 4; ++r) {
        const int m = m0 + wm + 16 * i + lg * 4 + r;
#pragma unroll
        for (int j = 0; j < 4; ++j)
          C[(size_t)m * D_MODEL + ncol[j]] = acc[i][j][r] + bj[j];
      }
  } else if (mode == 2) {
    u16* C = (u16*)Cptr;
#pragma unroll
    for (int i = 0; i < 4; ++i)
#pragma unroll
      for (int r = 0; r < 4; ++r) {
        const int m = m0 + wm + 16 * i + lg * 4 + r;
        const int b = m >> 11, s = m & (SEQ - 1);
#pragma unroll
        for (int j = 0; j < 4; ++j) {
          const int h = ncol[j] >> 7, d = ncol[j] & (DH - 1);
          C[((size_t)((b * NH + h) * DH + d)) * SEQ + s] = f2bf(acc[i][j][r] + bj[j]);
        }
      }
  } else {
    u16* C = (u16*)Cptr;
#pragma unroll
    for (int i = 0; i < 4; ++i)
#pragma unroll
      for (int r = 0; r < 4; ++r) {
        const int m = m0 + wm + 16 * i + lg * 4 + r;
        const int b = m >> 11, s = m & (SEQ - 1);
#pragma unroll
        for (int j = 0; j < 4; ++j) {
          const int h = ncol[j] >> 7, d = ncol[j] & (DH - 1);
          C[((size_t)((b * NH + h) * SEQ + s)) * DH + d] = f2bf(acc[i][j][r] + bj[j]);
        }
      }
  }
}

// ---------------------------------------------------------------------------
extern "C" void kernel_launch(void* const* d_in, const int* in_sizes, int n_in,
                              void* d_out, int out_size, void* d_ws,
                              size_t ws_size, hipStream_t stream) {
  const float* x = (const float*)d_in[0];
  const float* Wq = (const float*)d_in[1];
  const float* bq = (const float*)d_in[2];
  const float* Wk = (const float*)d_in[3];
  const float* bk = (const float*)d_in[4];
  const float* Wv = (const float*)d_in[5];
  const float* bv = (const float*)d_in[6];
  const float* Wo = (const float*)d_in[7];
  const float* bo = (const float*)d_in[8];
  float* out = (float*)d_out;

  const size_t E = (size_t)NBH * SEQ * DH;
  const size_t WE = (size_t)D_MODEL * D_MODEL;
  const size_t need = (4 * E + 3 * WE) * sizeof(u16);  // 92.3 MB

  const dim3 gb(256);

  if (ws_size >= need) {
    u16* xb = (u16*)d_ws;
    u16* wqb = xb + E;
    u16* wkb = wqb + WE;
    u16* wvb = wkb + WE;
    u16* q = wvb + WE;
    u16* k = q + E;
    u16* vt = k + E;
    u16* aflat = xb;  // xb dead after QKV GEMM
    u16* wob = q;     // q dead after attention

    cvt_kernel<<<dim3((int)(E / 2048)), gb, 0, stream>>>(x, xb, (int)E);
    cvt_kernel<<<dim3((int)(WE / 2048)), gb, 0, stream>>>(Wq, wqb, (int)WE);
    cvt_kernel<<<dim3((int)(WE / 2048)), gb, 0, stream>>>(Wk, wkb, (int)WE);
    cvt_kernel<<<dim3((int)(WE / 2048)), gb, 0, stream>>>(Wv, wvb, (int)WE);

    gemm_async<<<dim3(48, 32), gb, 0, stream>>>(xb, wqb, wkb, wvb, bq, bk, bv,
                                                q, k, vt, 1);
    rope_kernel<<<dim3((NBH * SEQ * (DH / 2)) / 256), gb, 0, stream>>>(q, k);
    attn_kernel<<<dim3(SEQ / 128, NBH), gb, 0, stream>>>(q, k, vt, aflat);
    cvt_kernel<<<dim3((int)(WE / 2048)), gb, 0, stream>>>(Wo, wob, (int)WE);
    gemm_async<<<dim3(16, 32), gb, 0, stream>>>(aflat, wob, nullptr, nullptr,
                                                bo, nullptr, nullptr, out,
                                                nullptr, nullptr, 0);
  } else {
    u16* q = (u16*)d_ws;
    u16* k = q + E;
    u16* vt = k + E;
    u16* aflat = vt + E;
    const dim3 gg(D_MODEL / 128, (2 * SEQ) / 128);
    gemm_kernel<0><<<gg, gb, 0, stream>>>(x, Wq, bq, q, 0);
    gemm_kernel<0><<<gg, gb, 0, stream>>>(x, Wk, bk, k, 1);
    gemm_kernel<0><<<gg, gb, 0, stream>>>(x, Wv, bv, vt, 2);
    rope_kernel<<<dim3((NBH * SEQ * (DH / 2)) / 256), dim3(256), 0, stream>>>(q, k);
    attn_kernel<<<dim3(SEQ / 128, NBH), gb, 0, stream>>>(q, k, vt, aflat);
    gemm_kernel<1><<<gg, gb, 0, stream>>>(aflat, Wo, bo, out, 3);
  }
}